// Round 5
// baseline (74.341 us; speedup 1.0000x reference)
//
#include <hip/hip_runtime.h>

#define DH 256
#define LQ 256

typedef __bf16 bf16x8 __attribute__((ext_vector_type(8)));
typedef float  f32x4  __attribute__((ext_vector_type(4)));

__device__ __forceinline__ bf16x8 cvt8(const float* __restrict__ p) {
    float4 a = *(const float4*)p;
    float4 b = *(const float4*)(p + 4);
    bf16x8 r;
    r[0] = (__bf16)a.x; r[1] = (__bf16)a.y; r[2] = (__bf16)a.z; r[3] = (__bf16)a.w;
    r[4] = (__bf16)b.x; r[5] = (__bf16)b.y; r[6] = (__bf16)b.z; r[7] = (__bf16)b.w;
    return r;
}

// MFMA 16x16x32 A/B fragment from f32 row-major [*][256]: lane l -> row0+(l&15), 8 k's
__device__ __forceinline__ bf16x8 ldfragf(const float* __restrict__ p, int row0, int k0, int lane) {
    const int r = row0 + (lane & 15);
    const int k = k0 + ((lane >> 4) << 3);
    return cvt8(p + r * DH + k);
}

// ---------- K1: rep = elu(X@Wfc^T+b); dep/head GEMMs; store rep + E_d/E_h (bh-major) ----------
__global__ __launch_bounds__(256) void k_front(
    const float* __restrict__ X, const float* __restrict__ Wfc, const float* __restrict__ bfc,
    const float* __restrict__ W1, const float* __restrict__ W2, const float* __restrict__ b1,
    float* __restrict__ rep_row, float* __restrict__ rep_t,
    float* __restrict__ Ed_t, float* __restrict__ Eh_t)
{
    __shared__ __bf16 repl[16][264];   // 16-token rep stripe, pad->2-way-max bank aliasing
    const int tid = threadIdx.x, wid = tid >> 6, lane = tid & 63;
    const int r0g = blockIdx.x * 16;   // global token-row base
    const int cw = wid * 64;           // wave's 64-col quarter
    const int b = r0g >> 8, tok0 = r0g & 255;
    const int lc = lane & 15, lr4 = (lane >> 4) << 2;

    const f32x4 z4 = {0.f, 0.f, 0.f, 0.f};
    f32x4 acc[4] = {z4, z4, z4, z4};
    for (int ks = 0; ks < 8; ++ks) {
        bf16x8 a = ldfragf(X, r0g, ks * 32, lane);
        #pragma unroll
        for (int ct = 0; ct < 4; ++ct) {
            bf16x8 w = ldfragf(Wfc, cw + ct * 16, ks * 32, lane);
            acc[ct] = __builtin_amdgcn_mfma_f32_16x16x32_bf16(a, w, acc[ct], 0, 0, 0);
        }
    }
    #pragma unroll
    for (int ct = 0; ct < 4; ++ct) {
        const int col = cw + ct * 16 + lc;
        const float bv = bfc[col];
        #pragma unroll
        for (int r = 0; r < 4; ++r) {
            const int rl = lr4 + r;
            float v = acc[ct][r] + bv;
            v = (v > 0.f) ? v : (__expf(v) - 1.f);
            repl[rl][col] = (__bf16)v;
            rep_row[(r0g + rl) * DH + col] = v;
            rep_t[((b << 8) + col) * LQ + tok0 + rl] = v;
        }
    }
    __syncthreads();

    f32x4 ad[4] = {z4, z4, z4, z4}, ah[4] = {z4, z4, z4, z4};
    for (int ks = 0; ks < 8; ++ks) {
        bf16x8 a = *(const bf16x8*)&repl[lane & 15][ks * 32 + ((lane >> 4) << 3)];
        #pragma unroll
        for (int ct = 0; ct < 4; ++ct) {
            bf16x8 u = ldfragf(W1, cw + ct * 16, ks * 32, lane);
            bf16x8 w = ldfragf(W2, cw + ct * 16, ks * 32, lane);
            ad[ct] = __builtin_amdgcn_mfma_f32_16x16x32_bf16(a, u, ad[ct], 0, 0, 0);
            ah[ct] = __builtin_amdgcn_mfma_f32_16x16x32_bf16(a, w, ah[ct], 0, 0, 0);
        }
    }
    #pragma unroll
    for (int ct = 0; ct < 4; ++ct) {
        const int col = cw + ct * 16 + lc;
        const float bb = b1[col];
        #pragma unroll
        for (int r = 0; r < 4; ++r) {
            const int tok = tok0 + lr4 + r;
            Ed_t[((b << 8) + col) * LQ + tok] = __expf(0.4f * (ad[ct][r] + bb)); // 2/C = 0.4
            Eh_t[((b << 8) + col) * LQ + tok] = __expf(0.4f * ah[ct][r]);
        }
    }
}

// ---------- K2: per-(b,h) masked channel-softmax; w_ij = exp2(A1*rcp(Ed_j*Eh_i+1)) ----------
// (scale-free: the exp2(+C*log2e) factor cancels in acc/s)
__global__ __launch_bounds__(64) void k_attn(
    const float* __restrict__ Ed_t, const float* __restrict__ Eh_t,
    const float* __restrict__ rep_t, float* __restrict__ attn_row)
{
    __shared__ float Ed[256];
    __shared__ float Rp[256];
    const int w = blockIdx.x & 3, bh = blockIdx.x >> 2;  // interleave heavy/light waves
    const int lane = threadIdx.x;
    const int j0 = lane * 4;
    *(float4*)&Ed[j0] = *(const float4*)(Ed_t + bh * LQ + j0);
    *(float4*)&Rp[j0] = *(const float4*)(rep_t + bh * LQ + j0);
    __syncthreads();
    const int i = w * 64 + lane;
    const float Eh = Eh_t[bh * LQ + i];
    const float A1 = -14.4269504f;                       // -2C*log2(e)
    float s = 0.f, acc = 0.f;
    for (int jb = 248; jb + 8 > w * 64; jb -= 8) {       // wave-uniform trip count
        #pragma unroll
        for (int u = 0; u < 8; ++u) {
            const int j = jb + u;
            float r = __builtin_amdgcn_rcpf(fmaf(Ed[j], Eh, 1.f));
            float e = __builtin_amdgcn_exp2f(A1 * r);
            e = (j > i) ? e : 0.f;
            s += e;
            acc = fmaf(e, Rp[j], acc);
        }
    }
    attn_row[(((bh >> 8) << 8) + i) * DH + (bh & 255)] = acc / (s + 1e-20f);
}

// ---------- K3: gate = sigmoid(rep@Wf1^T + attn@Wf2^T + bf); blend; mask ----------
__global__ __launch_bounds__(256) void k_gate(
    const float* __restrict__ rep_row, const float* __restrict__ attn_row,
    const float* __restrict__ Wf1, const float* __restrict__ Wf2,
    const float* __restrict__ bfv, const float* __restrict__ rmask,
    float* __restrict__ out)
{
    const int tid = threadIdx.x, wid = tid >> 6, lane = tid & 63;
    const int r0g = blockIdx.x * 16;
    const int cw = wid * 64;
    const int lc = lane & 15, lr4 = (lane >> 4) << 2;

    const f32x4 z4 = {0.f, 0.f, 0.f, 0.f};
    f32x4 acc[4] = {z4, z4, z4, z4};
    for (int ks = 0; ks < 8; ++ks) {
        bf16x8 a1 = ldfragf(rep_row,  r0g, ks * 32, lane);
        bf16x8 a2 = ldfragf(attn_row, r0g, ks * 32, lane);
        #pragma unroll
        for (int ct = 0; ct < 4; ++ct) {
            bf16x8 u = ldfragf(Wf1, cw + ct * 16, ks * 32, lane);
            bf16x8 w = ldfragf(Wf2, cw + ct * 16, ks * 32, lane);
            acc[ct] = __builtin_amdgcn_mfma_f32_16x16x32_bf16(a1, u, acc[ct], 0, 0, 0);
            acc[ct] = __builtin_amdgcn_mfma_f32_16x16x32_bf16(a2, w, acc[ct], 0, 0, 0);
        }
    }
    #pragma unroll
    for (int ct = 0; ct < 4; ++ct) {
        const int col = cw + ct * 16 + lc;
        const float bb = bfv[col];
        #pragma unroll
        for (int r = 0; r < 4; ++r) {
            const int row = r0g + lr4 + r;
            float z = acc[ct][r] + bb;
            float g = 1.f / (1.f + __expf(-z));
            float rv = rep_row[row * DH + col];
            float av = attn_row[row * DH + col];
            out[row * DH + col] = (g * rv + (1.f - g) * av) * rmask[row];
        }
    }
}

extern "C" void kernel_launch(void* const* d_in, const int* in_sizes, int n_in,
                              void* d_out, int out_size, void* d_ws, size_t ws_size,
                              hipStream_t stream) {
    const float* x    = (const float*)d_in[0];
    const float* rmsk = (const float*)d_in[1];
    const float* fc_w = (const float*)d_in[2];
    const float* fc_b = (const float*)d_in[3];
    const float* w1   = (const float*)d_in[4];
    const float* w2   = (const float*)d_in[5];
    const float* b1   = (const float*)d_in[6];
    const float* wf1  = (const float*)d_in[7];
    const float* wf2  = (const float*)d_in[8];
    const float* bfb  = (const float*)d_in[9];

    float* ws = (float*)d_ws;
    float* rep_row  = ws;                 // [1024][256] row-major
    float* rep_t    = ws + 1 * 262144;    // [b*256+h][256] token-major per channel
    float* Ed_t     = ws + 2 * 262144;    // exp(0.4*(dep+b1)), bh-major
    float* Eh_t     = ws + 3 * 262144;    // exp(0.4*head), bh-major
    float* attn_row = ws + 4 * 262144;    // [1024][256] row-major

    k_front<<<dim3(64), dim3(256), 0, stream>>>(x, fc_w, fc_b, w1, w2, b1,
                                                rep_row, rep_t, Ed_t, Eh_t);
    k_attn<<<dim3(4096), dim3(64), 0, stream>>>(Ed_t, Eh_t, rep_t, attn_row);
    k_gate<<<dim3(64), dim3(256), 0, stream>>>(rep_row, attn_row, wf1, wf2, bfb, rmsk,
                                               (float*)d_out);
}

// Round 6
// 36.677 us; speedup vs baseline: 2.0269x; 2.0269x over previous
//
#include <hip/hip_runtime.h>

#define DH 256
#define LQ 256

typedef __bf16 bf16x8 __attribute__((ext_vector_type(8)));
typedef __bf16 bf16x4 __attribute__((ext_vector_type(4)));
typedef float  f32x4  __attribute__((ext_vector_type(4)));

// ---- stage a 32-row x 256-col panel from f32 row-major global into LDS bf16 [32][264]
__device__ __forceinline__ void stage32f(const float* __restrict__ src, int row0,
                                         __bf16 (*dst)[264], int tid) {
    const int r = tid >> 3;
    #pragma unroll
    for (int c = 0; c < 4; ++c) {
        const int ch = (tid & 7) + 8 * c;            // 32 chunks of 8 floats per row
        const float* p = src + (row0 + r) * DH + ch * 8;
        float4 a = *(const float4*)p;
        float4 b = *(const float4*)(p + 4);
        bf16x8 v;
        v[0] = (__bf16)a.x; v[1] = (__bf16)a.y; v[2] = (__bf16)a.z; v[3] = (__bf16)a.w;
        v[4] = (__bf16)b.x; v[5] = (__bf16)b.y; v[6] = (__bf16)b.z; v[7] = (__bf16)b.w;
        *(bf16x8*)&dst[r][ch * 8] = v;
    }
}
// ---- same but bf16 source
__device__ __forceinline__ void stage32h(const __bf16* __restrict__ src, int row0,
                                         __bf16 (*dst)[264], int tid) {
    const int r = tid >> 3;
    #pragma unroll
    for (int c = 0; c < 4; ++c) {
        const int ch = (tid & 7) + 8 * c;
        *(bf16x8*)&dst[r][ch * 8] = *(const bf16x8*)&src[(row0 + r) * DH + ch * 8];
    }
}
// ---- MFMA 16x16x32 fragment from LDS panel: lane -> row r0+(l&15), k = ks*32+(l>>4)*8
__device__ __forceinline__ bf16x8 frag(const __bf16 (*m)[264], int r0, int ks, int lane) {
    return *(const bf16x8*)&m[r0 + (lane & 15)][ks * 32 + ((lane >> 4) << 3)];
}

// ---------- K1: rep = elu(X @ Wfc^T + b) -> rep_bf (row-major) + rep_t (bh-major) ----------
__global__ __launch_bounds__(256) void k_fc(
    const float* __restrict__ X, const float* __restrict__ Wfc, const float* __restrict__ bfc,
    __bf16* __restrict__ rep_bf, __bf16* __restrict__ rep_t)
{
    __shared__ __bf16 Xa[32][264];
    __shared__ __bf16 Wb[32][264];
    const int tid = threadIdx.x, lane = tid & 63, wid = tid >> 6;
    const int mb = blockIdx.x >> 3, nb = blockIdx.x & 7;
    const int r0 = mb * 32, c0 = nb * 32;
    stage32f(X, r0, Xa, tid);
    stage32f(Wfc, c0, Wb, tid);
    __syncthreads();
    const int wr = (wid >> 1) * 16, wc = (wid & 1) * 16;
    f32x4 acc = {0.f, 0.f, 0.f, 0.f};
    #pragma unroll
    for (int ks = 0; ks < 8; ++ks)
        acc = __builtin_amdgcn_mfma_f32_16x16x32_bf16(frag(Xa, wr, ks, lane),
                                                      frag(Wb, wc, ks, lane), acc, 0, 0, 0);
    const int col = c0 + wc + (lane & 15);
    const int row = r0 + wr + ((lane >> 4) << 2);
    const int b = row >> 8, tok = row & 255;
    const float bv = bfc[col];
    bf16x4 pk;
    #pragma unroll
    for (int r = 0; r < 4; ++r) {
        float v = acc[r] + bv;
        v = (v > 0.f) ? v : (__expf(v) - 1.f);
        __bf16 h = (__bf16)v;
        rep_bf[(row + r) * DH + col] = h;
        pk[r] = h;
    }
    *(bf16x4*)(rep_t + ((b << 8) + col) * LQ + tok) = pk;
}

// ---------- K2: Ed = exp(0.4*(rep@W1^T+b1)), Eh = exp(0.4*rep@W2^T)  (bh-major f32) ----------
__global__ __launch_bounds__(256) void k_dephead(
    const __bf16* __restrict__ rep_bf, const float* __restrict__ W1, const float* __restrict__ W2,
    const float* __restrict__ b1, float* __restrict__ Ed_t, float* __restrict__ Eh_t)
{
    __shared__ __bf16 Ra[32][264];
    __shared__ __bf16 U1[32][264];
    __shared__ __bf16 U2[32][264];
    const int tid = threadIdx.x, lane = tid & 63, wid = tid >> 6;
    const int mb = blockIdx.x >> 3, nb = blockIdx.x & 7;
    const int r0 = mb * 32, c0 = nb * 32;
    stage32h(rep_bf, r0, Ra, tid);
    stage32f(W1, c0, U1, tid);
    stage32f(W2, c0, U2, tid);
    __syncthreads();
    const int wr = (wid >> 1) * 16, wc = (wid & 1) * 16;
    f32x4 ad = {0.f, 0.f, 0.f, 0.f}, ah = {0.f, 0.f, 0.f, 0.f};
    #pragma unroll
    for (int ks = 0; ks < 8; ++ks) {
        bf16x8 a = frag(Ra, wr, ks, lane);
        ad = __builtin_amdgcn_mfma_f32_16x16x32_bf16(a, frag(U1, wc, ks, lane), ad, 0, 0, 0);
        ah = __builtin_amdgcn_mfma_f32_16x16x32_bf16(a, frag(U2, wc, ks, lane), ah, 0, 0, 0);
    }
    const int col = c0 + wc + (lane & 15);
    const int row = r0 + wr + ((lane >> 4) << 2);
    const int b = row >> 8, tok = row & 255;
    const float bb = b1[col];
    f32x4 ed, eh;
    #pragma unroll
    for (int r = 0; r < 4; ++r) {
        ed[r] = __expf(0.4f * (ad[r] + bb));   // 2/C = 0.4
        eh[r] = __expf(0.4f * ah[r]);
    }
    *(f32x4*)(Ed_t + ((b << 8) + col) * LQ + tok) = ed;
    *(f32x4*)(Eh_t + ((b << 8) + col) * LQ + tok) = eh;
}

// ---------- K3: per-(b,h) masked channel-softmax; w_ij = exp2(A1*rcp(Ed_j*Eh_i+1)) ----------
__global__ __launch_bounds__(64) void k_attn(
    const float* __restrict__ Ed_t, const float* __restrict__ Eh_t,
    const __bf16* __restrict__ rep_t, __bf16* __restrict__ attn_bf)
{
    __shared__ float Ed[256];
    __shared__ float Rp[256];
    const int w = blockIdx.x & 3, bh = blockIdx.x >> 2;   // interleave heavy/light waves
    const int lane = threadIdx.x;
    const int j0 = lane * 4;
    *(float4*)&Ed[j0] = *(const float4*)(Ed_t + bh * LQ + j0);
    bf16x4 rv = *(const bf16x4*)(rep_t + bh * LQ + j0);
    Rp[j0 + 0] = (float)rv[0]; Rp[j0 + 1] = (float)rv[1];
    Rp[j0 + 2] = (float)rv[2]; Rp[j0 + 3] = (float)rv[3];
    __syncthreads();
    const int i = w * 64 + lane;
    const float Eh = Eh_t[bh * LQ + i];
    const float A1 = -14.4269504f;                        // -2C*log2(e)
    float s = 0.f, acc = 0.f;
    for (int jb = 248; jb + 8 > w * 64; jb -= 8) {        // wave-uniform trip count
        #pragma unroll
        for (int u = 0; u < 8; ++u) {
            const int j = jb + u;
            float r = __builtin_amdgcn_rcpf(fmaf(Ed[j], Eh, 1.f));
            float e = __builtin_amdgcn_exp2f(A1 * r);
            e = (j > i) ? e : 0.f;
            s += e;
            acc = fmaf(e, Rp[j], acc);
        }
    }
    attn_bf[(((bh >> 8) << 8) + i) * DH + (bh & 255)] = (__bf16)(acc / (s + 1e-20f));
}

// ---------- K4: gate = sigmoid(rep@Wf1^T + attn@Wf2^T + bf); blend; mask ----------
__global__ __launch_bounds__(256) void k_gate(
    const __bf16* __restrict__ rep_bf, const __bf16* __restrict__ attn_bf,
    const float* __restrict__ Wf1, const float* __restrict__ Wf2,
    const float* __restrict__ bfv, const float* __restrict__ rmask,
    float* __restrict__ out)
{
    __shared__ __bf16 Ra[32][264];
    __shared__ __bf16 Aa[32][264];
    __shared__ __bf16 U1[32][264];
    __shared__ __bf16 U2[32][264];
    const int tid = threadIdx.x, lane = tid & 63, wid = tid >> 6;
    const int mb = blockIdx.x >> 3, nb = blockIdx.x & 7;
    const int r0 = mb * 32, c0 = nb * 32;
    stage32h(rep_bf, r0, Ra, tid);
    stage32h(attn_bf, r0, Aa, tid);
    stage32f(Wf1, c0, U1, tid);
    stage32f(Wf2, c0, U2, tid);
    __syncthreads();
    const int wr = (wid >> 1) * 16, wc = (wid & 1) * 16;
    f32x4 acc = {0.f, 0.f, 0.f, 0.f};
    #pragma unroll
    for (int ks = 0; ks < 8; ++ks) {
        acc = __builtin_amdgcn_mfma_f32_16x16x32_bf16(frag(Ra, wr, ks, lane),
                                                      frag(U1, wc, ks, lane), acc, 0, 0, 0);
        acc = __builtin_amdgcn_mfma_f32_16x16x32_bf16(frag(Aa, wr, ks, lane),
                                                      frag(U2, wc, ks, lane), acc, 0, 0, 0);
    }
    const int col = c0 + wc + (lane & 15);
    const int row = r0 + wr + ((lane >> 4) << 2);
    const float bb = bfv[col];
    #pragma unroll
    for (int r = 0; r < 4; ++r) {
        const int rr = row + r;
        float z = acc[r] + bb;
        float g = 1.f / (1.f + __expf(-z));
        float rv = (float)rep_bf[rr * DH + col];
        float av = (float)attn_bf[rr * DH + col];
        out[rr * DH + col] = (g * rv + (1.f - g) * av) * rmask[rr];
    }
}

extern "C" void kernel_launch(void* const* d_in, const int* in_sizes, int n_in,
                              void* d_out, int out_size, void* d_ws, size_t ws_size,
                              hipStream_t stream) {
    const float* x    = (const float*)d_in[0];
    const float* rmsk = (const float*)d_in[1];
    const float* fc_w = (const float*)d_in[2];
    const float* fc_b = (const float*)d_in[3];
    const float* w1   = (const float*)d_in[4];
    const float* w2   = (const float*)d_in[5];
    const float* b1   = (const float*)d_in[6];
    const float* wf1  = (const float*)d_in[7];
    const float* wf2  = (const float*)d_in[8];
    const float* bfb  = (const float*)d_in[9];

    char* ws = (char*)d_ws;
    __bf16* rep_bf  = (__bf16*)(ws);                  // 512 KB row-major
    __bf16* rep_t   = (__bf16*)(ws + (1u << 19));     // 512 KB bh-major
    __bf16* attn_bf = (__bf16*)(ws + (2u << 19));     // 512 KB row-major
    float*  Ed_t    = (float*)(ws + (3u << 19));      // 1 MB bh-major
    float*  Eh_t    = (float*)(ws + (5u << 19));      // 1 MB bh-major

    k_fc<<<dim3(256), dim3(256), 0, stream>>>(x, fc_w, fc_b, rep_bf, rep_t);
    k_dephead<<<dim3(256), dim3(256), 0, stream>>>(rep_bf, w1, w2, b1, Ed_t, Eh_t);
    k_attn<<<dim3(4096), dim3(64), 0, stream>>>(Ed_t, Eh_t, rep_t, attn_bf);
    k_gate<<<dim3(256), dim3(256), 0, stream>>>(rep_bf, attn_bf, wf1, wf2, bfb, rmsk,
                                                (float*)d_out);
}